// Round 3
// baseline (574.833 us; speedup 1.0000x reference)
//
#include <hip/hip_runtime.h>
#include <cmath>

typedef __bf16 bf16x8 __attribute__((ext_vector_type(8)));
typedef float f32x4 __attribute__((ext_vector_type(4)));
typedef unsigned short us8 __attribute__((ext_vector_type(8)));

__device__ __forceinline__ unsigned short f2bf(float f) {
    union { float f; unsigned u; } x; x.f = f;
    unsigned u = x.u + 0x7FFFu + ((x.u >> 16) & 1u);
    return (unsigned short)(u >> 16);
}
__device__ __forceinline__ float bf2f(unsigned short h) {
    union { unsigned u; float f; } x; x.u = ((unsigned)h) << 16;
    return x.f;
}

// load 8 consecutive fp32, convert to bf16x8 (as us8)
__device__ __forceinline__ us8 cvt8(const float* p) {
    f32x4 a = *(const f32x4*)p;
    f32x4 b = *(const f32x4*)(p + 4);
    union { bf16x8 h; us8 u; } cv;
    cv.h[0] = (__bf16)a[0]; cv.h[1] = (__bf16)a[1];
    cv.h[2] = (__bf16)a[2]; cv.h[3] = (__bf16)a[3];
    cv.h[4] = (__bf16)b[0]; cv.h[5] = (__bf16)b[1];
    cv.h[6] = (__bf16)b[2]; cv.h[7] = (__bf16)b[3];
    return cv.u;
}

// ---------------------------------------------------------------------------
// Projection GEMM (fp32 inputs): Y[m,n] = sum_k A[m,k]*W[n,k] + bias[n]
// M=16384, N=1024, K=1024.
// MODE 1: v = exp(clamp(y)); store transposed bf16 outT [B][1024][4096]; col sums -> S
// MODE 2: v = y;             store transposed bf16 outT
// ---------------------------------------------------------------------------
template<int MODE>
__global__ __launch_bounds__(256)
void gemm_proj(const float* __restrict__ A,
               const float* __restrict__ W,
               const float* __restrict__ bias,
               unsigned short* __restrict__ outT,
               float* __restrict__ S)
{
    __shared__ __align__(16) unsigned short lds[17408]; // staging 8192 | epilogue 128*136
    unsigned short* ldsA = lds;
    unsigned short* ldsB = lds + 4096;

    const int tid = threadIdx.x;
    const int wid = tid >> 6, lane = tid & 63;
    const int quad = lane >> 4, l16 = lane & 15;
    const int waveM = wid >> 1, waveN = wid & 1;
    const int m0 = blockIdx.y * 128, n0 = blockIdx.x * 128;
    const int srow = tid >> 2;          // 0..63
    const int scol = (tid & 3) * 8;     // 0,8,16,24

    f32x4 acc[4][4] = {};

    for (int k0 = 0; k0 < 1024; k0 += 32) {
        __syncthreads();
#pragma unroll
        for (int p = 0; p < 2; ++p) {
            const int row = p * 64 + srow;
            us8 va = cvt8(A + (size_t)(m0 + row) * 1024 + k0 + scol);
            us8 vw = cvt8(W + (size_t)(n0 + row) * 1024 + k0 + scol);
            *(us8*)(ldsA + row * 32 + scol) = va;
            *(us8*)(ldsB + row * 32 + scol) = vw;
        }
        __syncthreads();
        bf16x8 af[4], bfr[4];
#pragma unroll
        for (int i = 0; i < 4; ++i)
            af[i] = *(const bf16x8*)(ldsA + (waveM * 64 + i * 16 + l16) * 32 + quad * 8);
#pragma unroll
        for (int j = 0; j < 4; ++j)
            bfr[j] = *(const bf16x8*)(ldsB + (waveN * 64 + j * 16 + l16) * 32 + quad * 8);
#pragma unroll
        for (int i = 0; i < 4; ++i)
#pragma unroll
            for (int j = 0; j < 4; ++j)
                acc[i][j] = __builtin_amdgcn_mfma_f32_16x16x32_bf16(af[i], bfr[j], acc[i][j], 0, 0, 0);
    }

    __syncthreads();
    const int b = m0 >> 12, l0 = m0 & 4095;
#pragma unroll
    for (int j = 0; j < 4; ++j) {
        const int nn = waveN * 64 + j * 16 + l16;
        const float bc = bias[n0 + nn];
        float ssum = 0.f;
#pragma unroll
        for (int i = 0; i < 4; ++i)
#pragma unroll
            for (int r = 0; r < 4; ++r) {
                const int mm = waveM * 64 + i * 16 + quad * 4 + r;
                float v = acc[i][j][r] + bc;
                if (MODE == 1) v = expf(fminf(fmaxf(v, -30.f), 30.f)); // NaN/inf firewall
                lds[nn * 136 + mm] = f2bf(v);
                ssum += v;
            }
        if (MODE == 1) {
            ssum += __shfl_xor(ssum, 16);
            ssum += __shfl_xor(ssum, 32);
            if (lane < 16)
                atomicAdd(&S[(size_t)b * 1024 + n0 + waveN * 64 + j * 16 + lane], ssum);
        }
    }
    __syncthreads();
    const int seg = (tid & 15) * 8;
#pragma unroll
    for (int it = 0; it < 8; ++it) {
        const int nn = (tid >> 4) + it * 16;
        us8 v = *(const us8*)&lds[nn * 136 + seg];
        *(us8*)(outT + ((size_t)b * 1024 + n0 + nn) * 4096 + l0 + seg) = v;
    }
}

// ---------------------------------------------------------------------------
// Context: ctxf[b][h][e][d] += sum_l Vt[b][h*64+e][l] * Et[b][h*64+d][l]
// grid (Lchunk=4, h=16, b=4); each block covers 1024 of L, atomicAdd fp32.
// ---------------------------------------------------------------------------
__global__ __launch_bounds__(256)
void ctx_kernel(const unsigned short* __restrict__ Vt,
                const unsigned short* __restrict__ Et,
                float* __restrict__ ctxf)
{
    __shared__ __align__(16) unsigned short lds[4096];
    unsigned short* ldsA = lds;
    unsigned short* ldsB = lds + 2048;

    const int tid = threadIdx.x;
    const int wid = tid >> 6, lane = tid & 63;
    const int quad = lane >> 4, l16 = lane & 15;
    const int b = blockIdx.z, h = blockIdx.y;
    const int lbase = blockIdx.x * 1024;

    const unsigned short* Arow = Vt + ((size_t)b * 1024 + h * 64) * 4096; // rows e
    const unsigned short* Brow = Et + ((size_t)b * 1024 + h * 64) * 4096; // rows d

    const int srow = tid >> 2;
    const int scol = (tid & 3) * 8;

    f32x4 acc[4] = {};

    for (int k0 = 0; k0 < 1024; k0 += 32) {
        __syncthreads();
        us8 va = *(const us8*)(Arow + (size_t)srow * 4096 + lbase + k0 + scol);
        us8 vb = *(const us8*)(Brow + (size_t)srow * 4096 + lbase + k0 + scol);
        *(us8*)(ldsA + srow * 32 + scol) = va;
        *(us8*)(ldsB + srow * 32 + scol) = vb;
        __syncthreads();
        bf16x8 a = *(const bf16x8*)(ldsA + (wid * 16 + l16) * 32 + quad * 8);
#pragma unroll
        for (int j = 0; j < 4; ++j) {
            bf16x8 bb = *(const bf16x8*)(ldsB + (j * 16 + l16) * 32 + quad * 8);
            acc[j] = __builtin_amdgcn_mfma_f32_16x16x32_bf16(a, bb, acc[j], 0, 0, 0);
        }
    }
    float* base = ctxf + ((size_t)(b * 16 + h)) * 4096;
#pragma unroll
    for (int j = 0; j < 4; ++j)
#pragma unroll
        for (int r = 0; r < 4; ++r) {
            const int e = wid * 16 + quad * 4 + r;
            const int d = j * 16 + l16;
            atomicAdd(base + e * 64 + d, acc[j][r]);
        }
}

// ctxb[b][h][e][d] = bf16( ctxf / S[b][h*64+d] )
__global__ __launch_bounds__(256)
void ctx_norm(const float* __restrict__ ctxf, const float* __restrict__ S,
              unsigned short* __restrict__ ctxb)
{
    const int i = blockIdx.x * 256 + threadIdx.x; // 262144 total
    const int d = i & 63;
    const int bh = i >> 12;
    const int b = bh >> 4, h = bh & 15;
    ctxb[i] = f2bf(ctxf[i] / S[b * 1024 + h * 64 + d]);
}

// ---------------------------------------------------------------------------
// Fused Q-projection (fp32 in) + attention:
//   Qp = q@Wq^T + bq (128x128 tile), then per head (2 per tile):
//   att[l][h*64+e] = sum_d Qp[l][h*64+d] * ctxb[b][h][e][d]
//   ec==0: att = V - att
// ---------------------------------------------------------------------------
__global__ __launch_bounds__(256)
void gemm_qattn(const float* __restrict__ A,
                const float* __restrict__ W,
                const float* __restrict__ bias,
                const unsigned short* __restrict__ ctxb,
                const unsigned short* __restrict__ Vt,
                const int* __restrict__ ec,
                unsigned short* __restrict__ att)
{
    __shared__ __align__(16) unsigned short lds[26624];
    unsigned short* ldsA = lds;
    unsigned short* ldsB = lds + 4096;
    unsigned short* ldsQ = lds;              // [128][136] after main loop
    unsigned short* ldsC = lds + 17408;      // [128][72] ctx rows

    const int tid = threadIdx.x;
    const int wid = tid >> 6, lane = tid & 63;
    const int quad = lane >> 4, l16 = lane & 15;
    const int waveM = wid >> 1, waveN = wid & 1;
    const int m0 = blockIdx.y * 128, n0 = blockIdx.x * 128;
    const int b = m0 >> 12;
    const int srow = tid >> 2, scol = (tid & 3) * 8;

    { // stage ctx for both heads of this tile
        const int e2 = tid >> 1;
        const int sg = (tid & 1) * 32;
        const unsigned short* src = ctxb +
            (((size_t)(b * 16) + (n0 >> 6) + (e2 >> 6)) * 64 + (e2 & 63)) * 64 + sg;
#pragma unroll
        for (int u = 0; u < 4; ++u)
            *(us8*)&ldsC[e2 * 72 + sg + u * 8] = *(const us8*)(src + u * 8);
    }

    f32x4 acc[4][4] = {};

    for (int k0 = 0; k0 < 1024; k0 += 32) {
        __syncthreads();
#pragma unroll
        for (int p = 0; p < 2; ++p) {
            const int row = p * 64 + srow;
            us8 va = cvt8(A + (size_t)(m0 + row) * 1024 + k0 + scol);
            us8 vw = cvt8(W + (size_t)(n0 + row) * 1024 + k0 + scol);
            *(us8*)(ldsA + row * 32 + scol) = va;
            *(us8*)(ldsB + row * 32 + scol) = vw;
        }
        __syncthreads();
        bf16x8 af[4], bfr[4];
#pragma unroll
        for (int i = 0; i < 4; ++i)
            af[i] = *(const bf16x8*)(ldsA + (waveM * 64 + i * 16 + l16) * 32 + quad * 8);
#pragma unroll
        for (int j = 0; j < 4; ++j)
            bfr[j] = *(const bf16x8*)(ldsB + (waveN * 64 + j * 16 + l16) * 32 + quad * 8);
#pragma unroll
        for (int i = 0; i < 4; ++i)
#pragma unroll
            for (int j = 0; j < 4; ++j)
                acc[i][j] = __builtin_amdgcn_mfma_f32_16x16x32_bf16(af[i], bfr[j], acc[i][j], 0, 0, 0);
    }

    __syncthreads();
#pragma unroll
    for (int j = 0; j < 4; ++j) {
        const int nn = waveN * 64 + j * 16 + l16;
        const float bc = bias[n0 + nn];
#pragma unroll
        for (int i = 0; i < 4; ++i)
#pragma unroll
            for (int r = 0; r < 4; ++r) {
                const int mm = waveM * 64 + i * 16 + quad * 4 + r;
                ldsQ[mm * 136 + nn] = f2bf(acc[i][j][r] + bc);
            }
    }
    __syncthreads();

    f32x4 acc2[4][4] = {};
#pragma unroll
    for (int ks = 0; ks < 64; ks += 32) {
        bf16x8 aq[4], cq[4];
#pragma unroll
        for (int i = 0; i < 4; ++i)
            aq[i] = *(const bf16x8*)&ldsQ[(waveM * 64 + i * 16 + l16) * 136 + waveN * 64 + ks + quad * 8];
#pragma unroll
        for (int j = 0; j < 4; ++j)
            cq[j] = *(const bf16x8*)&ldsC[(waveN * 64 + j * 16 + l16) * 72 + ks + quad * 8];
#pragma unroll
        for (int i = 0; i < 4; ++i)
#pragma unroll
            for (int j = 0; j < 4; ++j)
                acc2[i][j] = __builtin_amdgcn_mfma_f32_16x16x32_bf16(aq[i], cq[j], acc2[i][j], 0, 0, 0);
    }

    const int common = ec[0];
#pragma unroll
    for (int i = 0; i < 4; ++i)
#pragma unroll
        for (int j = 0; j < 4; ++j)
#pragma unroll
            for (int r = 0; r < 4; ++r) {
                const int lrow = m0 + waveM * 64 + i * 16 + quad * 4 + r;
                const int chan = n0 + waveN * 64 + j * 16 + l16;
                float vv = acc2[i][j][r];
                if (!common)
                    vv = bf2f(Vt[((size_t)(lrow >> 12) * 1024 + chan) * 4096 + (lrow & 4095)]) - vv;
                att[(size_t)lrow * 1024 + chan] = f2bf(vv);
            }
}

// ---------------------------------------------------------------------------
// Output GEMM: out[m,n] = sum_k att[m,k]*Wo[n,k] + bo[n]; att bf16, Wo fp32,
// out fp32 (d_out).
// ---------------------------------------------------------------------------
__global__ __launch_bounds__(256)
void gemm_out(const unsigned short* __restrict__ A,
              const float* __restrict__ W,
              const float* __restrict__ bias,
              float* __restrict__ outP)
{
    __shared__ __align__(16) unsigned short lds[8192];
    unsigned short* ldsA = lds;
    unsigned short* ldsB = lds + 4096;

    const int tid = threadIdx.x;
    const int wid = tid >> 6, lane = tid & 63;
    const int quad = lane >> 4, l16 = lane & 15;
    const int waveM = wid >> 1, waveN = wid & 1;
    const int m0 = blockIdx.y * 128, n0 = blockIdx.x * 128;
    const int srow = tid >> 2, scol = (tid & 3) * 8;

    f32x4 acc[4][4] = {};

    for (int k0 = 0; k0 < 1024; k0 += 32) {
        __syncthreads();
#pragma unroll
        for (int p = 0; p < 2; ++p) {
            const int row = p * 64 + srow;
            us8 va = *(const us8*)(A + (size_t)(m0 + row) * 1024 + k0 + scol);
            us8 vw = cvt8(W + (size_t)(n0 + row) * 1024 + k0 + scol);
            *(us8*)(ldsA + row * 32 + scol) = va;
            *(us8*)(ldsB + row * 32 + scol) = vw;
        }
        __syncthreads();
        bf16x8 af[4], bfr[4];
#pragma unroll
        for (int i = 0; i < 4; ++i)
            af[i] = *(const bf16x8*)(ldsA + (waveM * 64 + i * 16 + l16) * 32 + quad * 8);
#pragma unroll
        for (int j = 0; j < 4; ++j)
            bfr[j] = *(const bf16x8*)(ldsB + (waveN * 64 + j * 16 + l16) * 32 + quad * 8);
#pragma unroll
        for (int i = 0; i < 4; ++i)
#pragma unroll
            for (int j = 0; j < 4; ++j)
                acc[i][j] = __builtin_amdgcn_mfma_f32_16x16x32_bf16(af[i], bfr[j], acc[i][j], 0, 0, 0);
    }

#pragma unroll
    for (int j = 0; j < 4; ++j) {
        const int col = n0 + waveN * 64 + j * 16 + l16;
        const float bc = bias[col];
#pragma unroll
        for (int i = 0; i < 4; ++i)
#pragma unroll
            for (int r = 0; r < 4; ++r) {
                const int row = m0 + waveM * 64 + i * 16 + quad * 4 + r;
                outP[(size_t)row * 1024 + col] = acc[i][j][r] + bc;
            }
    }
}

// ---------------------------------------------------------------------------
extern "C" void kernel_launch(void* const* d_in, const int* in_sizes, int n_in,
                              void* d_out, int out_size, void* d_ws, size_t ws_size,
                              hipStream_t stream)
{
    const float* q  = (const float*)d_in[0];
    const float* k  = (const float*)d_in[1];
    const float* v  = (const float*)d_in[2];
    const float* Wq = (const float*)d_in[3];
    const float* bq = (const float*)d_in[4];
    const float* Wk = (const float*)d_in[5];
    const float* bk = (const float*)d_in[6];
    const float* Wv = (const float*)d_in[7];
    const float* bv = (const float*)d_in[8];
    const float* Wo = (const float*)d_in[9];
    const float* bo = (const float*)d_in[10];
    const int* ec   = (const int*)d_in[11];

    // workspace map (≈68.7 MB total)
    char* ws = (char*)d_ws;
    unsigned short* Et   = (unsigned short*)(ws);                 // 33.55 MB [4][1024][4096]
    unsigned short* Vt   = (unsigned short*)(ws + 33554432);      // 33.55 MB [4][1024][4096]
    float*          ctxf = (float*)(ws + 67108864);               // 1 MB [4][16][64][64]
    float*          S    = (float*)(ws + 68157440);               // 16 KB [4][1024]
    unsigned short* ctxb = (unsigned short*)(ws + 68173824);      // 0.5 MB
    unsigned short* att  = Et;                                    // alias (Et dead after ctx)

    hipMemsetAsync(S, 0, 4096 * sizeof(float), stream);
    hipMemsetAsync(ctxf, 0, 4 * 16 * 64 * 64 * sizeof(float), stream);

    dim3 gblk(8, 128, 1);
    gemm_proj<1><<<gblk, 256, 0, stream>>>(k, Wk, bk, Et, S);
    gemm_proj<2><<<gblk, 256, 0, stream>>>(v, Wv, bv, Vt, nullptr);

    ctx_kernel<<<dim3(4, 16, 4), 256, 0, stream>>>(Vt, Et, ctxf);
    ctx_norm<<<1024, 256, 0, stream>>>(ctxf, S, ctxb);

    gemm_qattn<<<gblk, 256, 0, stream>>>(q, Wq, bq, ctxb, Vt, ec, att);

    gemm_out<<<gblk, 256, 0, stream>>>(att, Wo, bo, (float*)d_out);
}

// Round 4
// 510.104 us; speedup vs baseline: 1.1269x; 1.1269x over previous
//
#include <hip/hip_runtime.h>
#include <cmath>

typedef __bf16 bf16x8 __attribute__((ext_vector_type(8)));
typedef float f32x4 __attribute__((ext_vector_type(4)));
typedef unsigned short us8 __attribute__((ext_vector_type(8)));

__device__ __forceinline__ unsigned short f2bf(float f) {
    union { float f; unsigned u; } x; x.f = f;
    unsigned u = x.u + 0x7FFFu + ((x.u >> 16) & 1u);
    return (unsigned short)(u >> 16);
}
__device__ __forceinline__ float bf2f(unsigned short h) {
    union { unsigned u; float f; } x; x.u = ((unsigned)h) << 16;
    return x.f;
}

// load 8 consecutive fp32, convert to bf16x8 (as us8)
__device__ __forceinline__ us8 cvt8(const float* p) {
    f32x4 a = *(const f32x4*)p;
    f32x4 b = *(const f32x4*)(p + 4);
    union { bf16x8 h; us8 u; } cv;
    cv.h[0] = (__bf16)a[0]; cv.h[1] = (__bf16)a[1];
    cv.h[2] = (__bf16)a[2]; cv.h[3] = (__bf16)a[3];
    cv.h[4] = (__bf16)b[0]; cv.h[5] = (__bf16)b[1];
    cv.h[6] = (__bf16)b[2]; cv.h[7] = (__bf16)b[3];
    return cv.u;
}

__device__ __forceinline__ void gl2lds16(const unsigned short* g, unsigned short* l) {
    __builtin_amdgcn_global_load_lds(
        (const __attribute__((address_space(1))) unsigned int*)g,
        (__attribute__((address_space(3))) unsigned int*)l, 16, 0, 0);
}

// fp32 -> bf16 elementwise, 8 elems/thread, exact-size grid
__global__ __launch_bounds__(256)
void cvt_kernel(const float* __restrict__ src, unsigned short* __restrict__ dst) {
    const size_t i = ((size_t)blockIdx.x * 256 + threadIdx.x) * 8;
    *(us8*)(dst + i) = cvt8(src + i);
}

// ---------------------------------------------------------------------------
// Projection GEMM: Y[m,n] = sum_k A[m,k]*W[n,k] + bias[n]; M=16384,N=1024,K=1024
// BF=true: A,W bf16, global_load_lds staging. BF=false: fp32 + inline cvt.
// MODE 1: v = exp(clamp(y)); transposed bf16 outT [B][1024][4096]; col sums->S
// MODE 2: v = y;             transposed bf16 outT
// ---------------------------------------------------------------------------
template<int MODE, bool BF>
__global__ __launch_bounds__(256)
void gemm_proj(const void* __restrict__ Ap, const void* __restrict__ Wp,
               const float* __restrict__ bias,
               unsigned short* __restrict__ outT,
               float* __restrict__ S)
{
    __shared__ __align__(16) unsigned short lds[17408]; // staging 8192 | epilogue 128*136
    unsigned short* ldsA = lds;
    unsigned short* ldsB = lds + 4096;

    const int tid = threadIdx.x;
    const int wid = tid >> 6, lane = tid & 63;
    const int quad = lane >> 4, l16 = lane & 15;
    const int waveM = wid >> 1, waveN = wid & 1;
    const int m0 = blockIdx.y * 128, n0 = blockIdx.x * 128;
    const int srow = tid >> 2;          // manual path: 0..63
    const int scol = (tid & 3) * 8;
    const int r4 = lane >> 2, c8 = (lane & 3) * 8; // gl2lds path

    f32x4 acc[4][4] = {};

    for (int k0 = 0; k0 < 1024; k0 += 32) {
        __syncthreads();
        if (BF) {
            const unsigned short* A = (const unsigned short*)Ap;
            const unsigned short* W = (const unsigned short*)Wp;
            for (int s = wid; s < 8; s += 4) {
                const int row = s * 16 + r4;
                gl2lds16(A + (size_t)(m0 + row) * 1024 + k0 + c8, ldsA + s * 512);
                gl2lds16(W + (size_t)(n0 + row) * 1024 + k0 + c8, ldsB + s * 512);
            }
        } else {
            const float* A = (const float*)Ap;
            const float* W = (const float*)Wp;
#pragma unroll
            for (int p = 0; p < 2; ++p) {
                const int row = p * 64 + srow;
                *(us8*)(ldsA + row * 32 + scol) = cvt8(A + (size_t)(m0 + row) * 1024 + k0 + scol);
                *(us8*)(ldsB + row * 32 + scol) = cvt8(W + (size_t)(n0 + row) * 1024 + k0 + scol);
            }
        }
        __syncthreads();
        bf16x8 af[4], bfr[4];
#pragma unroll
        for (int i = 0; i < 4; ++i)
            af[i] = *(const bf16x8*)(ldsA + (waveM * 64 + i * 16 + l16) * 32 + quad * 8);
#pragma unroll
        for (int j = 0; j < 4; ++j)
            bfr[j] = *(const bf16x8*)(ldsB + (waveN * 64 + j * 16 + l16) * 32 + quad * 8);
#pragma unroll
        for (int i = 0; i < 4; ++i)
#pragma unroll
            for (int j = 0; j < 4; ++j)
                acc[i][j] = __builtin_amdgcn_mfma_f32_16x16x32_bf16(af[i], bfr[j], acc[i][j], 0, 0, 0);
    }

    __syncthreads();
    const int b = m0 >> 12, l0 = m0 & 4095;
#pragma unroll
    for (int j = 0; j < 4; ++j) {
        const int nn = waveN * 64 + j * 16 + l16;
        const float bc = bias[n0 + nn];
        float ssum = 0.f;
#pragma unroll
        for (int i = 0; i < 4; ++i)
#pragma unroll
            for (int r = 0; r < 4; ++r) {
                const int mm = waveM * 64 + i * 16 + quad * 4 + r;
                float v = acc[i][j][r] + bc;
                if (MODE == 1) v = expf(fminf(fmaxf(v, -30.f), 30.f)); // NaN/inf firewall
                lds[nn * 136 + mm] = f2bf(v);
                ssum += v;
            }
        if (MODE == 1) {
            ssum += __shfl_xor(ssum, 16);
            ssum += __shfl_xor(ssum, 32);
            if (lane < 16)
                atomicAdd(&S[(size_t)b * 1024 + n0 + waveN * 64 + j * 16 + lane], ssum);
        }
    }
    __syncthreads();
    const int seg = (tid & 15) * 8;
#pragma unroll
    for (int it = 0; it < 8; ++it) {
        const int nn = (tid >> 4) + it * 16;
        us8 v = *(const us8*)&lds[nn * 136 + seg];
        *(us8*)(outT + ((size_t)b * 1024 + n0 + nn) * 4096 + l0 + seg) = v;
    }
}

// ---------------------------------------------------------------------------
// Context: ctxf[b][h][e][d] += sum_l Vt[b][h*64+e][l] * Et[b][h*64+d][l]
// ---------------------------------------------------------------------------
__global__ __launch_bounds__(256)
void ctx_kernel(const unsigned short* __restrict__ Vt,
                const unsigned short* __restrict__ Et,
                float* __restrict__ ctxf)
{
    __shared__ __align__(16) unsigned short lds[4096];
    unsigned short* ldsA = lds;
    unsigned short* ldsB = lds + 2048;

    const int tid = threadIdx.x;
    const int wid = tid >> 6, lane = tid & 63;
    const int quad = lane >> 4, l16 = lane & 15;
    const int b = blockIdx.z, h = blockIdx.y;
    const int lbase = blockIdx.x * 1024;

    const unsigned short* Arow = Vt + ((size_t)b * 1024 + h * 64) * 4096; // rows e
    const unsigned short* Brow = Et + ((size_t)b * 1024 + h * 64) * 4096; // rows d

    const int srow = tid >> 2;
    const int scol = (tid & 3) * 8;

    f32x4 acc[4] = {};

    for (int k0 = 0; k0 < 1024; k0 += 32) {
        __syncthreads();
        us8 va = *(const us8*)(Arow + (size_t)srow * 4096 + lbase + k0 + scol);
        us8 vb = *(const us8*)(Brow + (size_t)srow * 4096 + lbase + k0 + scol);
        *(us8*)(ldsA + srow * 32 + scol) = va;
        *(us8*)(ldsB + srow * 32 + scol) = vb;
        __syncthreads();
        bf16x8 a = *(const bf16x8*)(ldsA + (wid * 16 + l16) * 32 + quad * 8);
#pragma unroll
        for (int j = 0; j < 4; ++j) {
            bf16x8 bb = *(const bf16x8*)(ldsB + (j * 16 + l16) * 32 + quad * 8);
            acc[j] = __builtin_amdgcn_mfma_f32_16x16x32_bf16(a, bb, acc[j], 0, 0, 0);
        }
    }
    float* base = ctxf + ((size_t)(b * 16 + h)) * 4096;
#pragma unroll
    for (int j = 0; j < 4; ++j)
#pragma unroll
        for (int r = 0; r < 4; ++r) {
            const int e = wid * 16 + quad * 4 + r;
            const int d = j * 16 + l16;
            atomicAdd(base + e * 64 + d, acc[j][r]);
        }
}

__global__ __launch_bounds__(256)
void ctx_norm(const float* __restrict__ ctxf, const float* __restrict__ S,
              unsigned short* __restrict__ ctxb)
{
    const int i = blockIdx.x * 256 + threadIdx.x; // 262144 total
    const int d = i & 63;
    const int bh = i >> 12;
    const int b = bh >> 4, h = bh & 15;
    ctxb[i] = f2bf(ctxf[i] / S[b * 1024 + h * 64 + d]);
}

// ---------------------------------------------------------------------------
// Fused Q-projection + attention (two heads per 128-col tile)
// ---------------------------------------------------------------------------
template<bool BF>
__global__ __launch_bounds__(256)
void gemm_qattn(const void* __restrict__ Ap, const void* __restrict__ Wp,
                const float* __restrict__ bias,
                const unsigned short* __restrict__ ctxb,
                const unsigned short* __restrict__ Vt,
                const int* __restrict__ ec,
                unsigned short* __restrict__ att)
{
    __shared__ __align__(16) unsigned short lds[26624];
    unsigned short* ldsA = lds;
    unsigned short* ldsB = lds + 4096;
    unsigned short* ldsQ = lds;              // [128][136] after main loop
    unsigned short* ldsC = lds + 17408;      // [128][72] ctx rows

    const int tid = threadIdx.x;
    const int wid = tid >> 6, lane = tid & 63;
    const int quad = lane >> 4, l16 = lane & 15;
    const int waveM = wid >> 1, waveN = wid & 1;
    const int m0 = blockIdx.y * 128, n0 = blockIdx.x * 128;
    const int b = m0 >> 12;
    const int srow = tid >> 2, scol = (tid & 3) * 8;
    const int r4 = lane >> 2, c8 = (lane & 3) * 8;

    { // stage ctx for both heads of this tile
        const int e2 = tid >> 1;
        const int sg = (tid & 1) * 32;
        const unsigned short* src = ctxb +
            (((size_t)(b * 16) + (n0 >> 6) + (e2 >> 6)) * 64 + (e2 & 63)) * 64 + sg;
#pragma unroll
        for (int u = 0; u < 4; ++u)
            *(us8*)&ldsC[e2 * 72 + sg + u * 8] = *(const us8*)(src + u * 8);
    }

    f32x4 acc[4][4] = {};

    for (int k0 = 0; k0 < 1024; k0 += 32) {
        __syncthreads();
        if (BF) {
            const unsigned short* A = (const unsigned short*)Ap;
            const unsigned short* W = (const unsigned short*)Wp;
            for (int s = wid; s < 8; s += 4) {
                const int row = s * 16 + r4;
                gl2lds16(A + (size_t)(m0 + row) * 1024 + k0 + c8, ldsA + s * 512);
                gl2lds16(W + (size_t)(n0 + row) * 1024 + k0 + c8, ldsB + s * 512);
            }
        } else {
            const float* A = (const float*)Ap;
            const float* W = (const float*)Wp;
#pragma unroll
            for (int p = 0; p < 2; ++p) {
                const int row = p * 64 + srow;
                *(us8*)(ldsA + row * 32 + scol) = cvt8(A + (size_t)(m0 + row) * 1024 + k0 + scol);
                *(us8*)(ldsB + row * 32 + scol) = cvt8(W + (size_t)(n0 + row) * 1024 + k0 + scol);
            }
        }
        __syncthreads();
        bf16x8 af[4], bfr[4];
#pragma unroll
        for (int i = 0; i < 4; ++i)
            af[i] = *(const bf16x8*)(ldsA + (waveM * 64 + i * 16 + l16) * 32 + quad * 8);
#pragma unroll
        for (int j = 0; j < 4; ++j)
            bfr[j] = *(const bf16x8*)(ldsB + (waveN * 64 + j * 16 + l16) * 32 + quad * 8);
#pragma unroll
        for (int i = 0; i < 4; ++i)
#pragma unroll
            for (int j = 0; j < 4; ++j)
                acc[i][j] = __builtin_amdgcn_mfma_f32_16x16x32_bf16(af[i], bfr[j], acc[i][j], 0, 0, 0);
    }

    __syncthreads();
#pragma unroll
    for (int j = 0; j < 4; ++j) {
        const int nn = waveN * 64 + j * 16 + l16;
        const float bc = bias[n0 + nn];
#pragma unroll
        for (int i = 0; i < 4; ++i)
#pragma unroll
            for (int r = 0; r < 4; ++r) {
                const int mm = waveM * 64 + i * 16 + quad * 4 + r;
                ldsQ[mm * 136 + nn] = f2bf(acc[i][j][r] + bc);
            }
    }
    __syncthreads();

    f32x4 acc2[4][4] = {};
#pragma unroll
    for (int ks = 0; ks < 64; ks += 32) {
        bf16x8 aq[4], cq[4];
#pragma unroll
        for (int i = 0; i < 4; ++i)
            aq[i] = *(const bf16x8*)&ldsQ[(waveM * 64 + i * 16 + l16) * 136 + waveN * 64 + ks + quad * 8];
#pragma unroll
        for (int j = 0; j < 4; ++j)
            cq[j] = *(const bf16x8*)&ldsC[(waveN * 64 + j * 16 + l16) * 72 + ks + quad * 8];
#pragma unroll
        for (int i = 0; i < 4; ++i)
#pragma unroll
            for (int j = 0; j < 4; ++j)
                acc2[i][j] = __builtin_amdgcn_mfma_f32_16x16x32_bf16(aq[i], cq[j], acc2[i][j], 0, 0, 0);
    }

    const int common = ec[0];
#pragma unroll
    for (int i = 0; i < 4; ++i)
#pragma unroll
        for (int j = 0; j < 4; ++j)
#pragma unroll
            for (int r = 0; r < 4; ++r) {
                const int lrow = m0 + waveM * 64 + i * 16 + quad * 4 + r;
                const int chan = n0 + waveN * 64 + j * 16 + l16;
                float vv = acc2[i][j][r];
                if (!common)
                    vv = bf2f(Vt[((size_t)(lrow >> 12) * 1024 + chan) * 4096 + (lrow & 4095)]) - vv;
                att[(size_t)lrow * 1024 + chan] = f2bf(vv);
            }
}

// ---------------------------------------------------------------------------
// Output GEMM: out[m,n] = sum_k att[m,k]*Wo[n,k] + bo[n]; out fp32.
// ---------------------------------------------------------------------------
template<bool BF>
__global__ __launch_bounds__(256)
void gemm_out(const unsigned short* __restrict__ A, const void* __restrict__ Wp,
              const float* __restrict__ bias,
              float* __restrict__ outP)
{
    __shared__ __align__(16) unsigned short lds[8192];
    unsigned short* ldsA = lds;
    unsigned short* ldsB = lds + 4096;

    const int tid = threadIdx.x;
    const int wid = tid >> 6, lane = tid & 63;
    const int quad = lane >> 4, l16 = lane & 15;
    const int waveM = wid >> 1, waveN = wid & 1;
    const int m0 = blockIdx.y * 128, n0 = blockIdx.x * 128;
    const int srow = tid >> 2, scol = (tid & 3) * 8;
    const int r4 = lane >> 2, c8 = (lane & 3) * 8;

    f32x4 acc[4][4] = {};

    for (int k0 = 0; k0 < 1024; k0 += 32) {
        __syncthreads();
        if (BF) {
            const unsigned short* W = (const unsigned short*)Wp;
            for (int s = wid; s < 8; s += 4) {
                const int row = s * 16 + r4;
                gl2lds16(A + (size_t)(m0 + row) * 1024 + k0 + c8, ldsA + s * 512);
                gl2lds16(W + (size_t)(n0 + row) * 1024 + k0 + c8, ldsB + s * 512);
            }
        } else {
            const float* W = (const float*)Wp;
#pragma unroll
            for (int p = 0; p < 2; ++p) {
                const int row = p * 64 + srow;
                *(us8*)(ldsA + row * 32 + scol) = *(const us8*)(A + (size_t)(m0 + row) * 1024 + k0 + scol);
                *(us8*)(ldsB + row * 32 + scol) = cvt8(W + (size_t)(n0 + row) * 1024 + k0 + scol);
            }
        }
        __syncthreads();
        bf16x8 af[4], bfr[4];
#pragma unroll
        for (int i = 0; i < 4; ++i)
            af[i] = *(const bf16x8*)(ldsA + (waveM * 64 + i * 16 + l16) * 32 + quad * 8);
#pragma unroll
        for (int j = 0; j < 4; ++j)
            bfr[j] = *(const bf16x8*)(ldsB + (waveN * 64 + j * 16 + l16) * 32 + quad * 8);
#pragma unroll
        for (int i = 0; i < 4; ++i)
#pragma unroll
            for (int j = 0; j < 4; ++j)
                acc[i][j] = __builtin_amdgcn_mfma_f32_16x16x32_bf16(af[i], bfr[j], acc[i][j], 0, 0, 0);
    }

#pragma unroll
    for (int j = 0; j < 4; ++j) {
        const int col = n0 + waveN * 64 + j * 16 + l16;
        const float bc = bias[col];
#pragma unroll
        for (int i = 0; i < 4; ++i)
#pragma unroll
            for (int r = 0; r < 4; ++r) {
                const int row = m0 + waveM * 64 + i * 16 + quad * 4 + r;
                outP[(size_t)row * 1024 + col] = acc[i][j][r] + bc;
            }
    }
}

// ---------------------------------------------------------------------------
extern "C" void kernel_launch(void* const* d_in, const int* in_sizes, int n_in,
                              void* d_out, int out_size, void* d_ws, size_t ws_size,
                              hipStream_t stream)
{
    const float* q  = (const float*)d_in[0];
    const float* k  = (const float*)d_in[1];
    const float* v  = (const float*)d_in[2];
    const float* Wq = (const float*)d_in[3];
    const float* bq = (const float*)d_in[4];
    const float* Wk = (const float*)d_in[5];
    const float* bk = (const float*)d_in[6];
    const float* Wv = (const float*)d_in[7];
    const float* bv = (const float*)d_in[8];
    const float* Wo = (const float*)d_in[9];
    const float* bo = (const float*)d_in[10];
    const int* ec   = (const int*)d_in[11];

    char* ws = (char*)d_ws;
    const size_t NEED_FAST = 110641152; // Ab+Et+Vt+Wb+ctxf+S+ctxb
    const dim3 gblk(8, 128, 1);

    if (ws_size >= NEED_FAST) {
        unsigned short* Ab   = (unsigned short*)(ws);                 // 33.55 MB (reused k,v,q)
        unsigned short* Et   = (unsigned short*)(ws + 33554432);      // 33.55 MB
        unsigned short* Vt   = (unsigned short*)(ws + 67108864);      // 33.55 MB
        unsigned short* Wkb  = (unsigned short*)(ws + 100663296);     // 2 MB
        unsigned short* Wvb  = (unsigned short*)(ws + 102760448);     // 2 MB
        unsigned short* Wqb  = (unsigned short*)(ws + 104857600);     // 2 MB
        unsigned short* Wob  = (unsigned short*)(ws + 106954752);     // 2 MB
        float*          ctxf = (float*)(ws + 109051904);              // 1 MB
        float*          S    = (float*)(ws + 110100480);              // 16 KB
        unsigned short* ctxb = (unsigned short*)(ws + 110116864);     // 0.5 MB
        unsigned short* att  = Et;                                    // alias (Et dead after ctx)

        hipMemsetAsync(S, 0, 4096 * sizeof(float), stream);
        hipMemsetAsync(ctxf, 0, 4 * 16 * 64 * 64 * sizeof(float), stream);

        cvt_kernel<<<512, 256, 0, stream>>>(Wk, Wkb);
        cvt_kernel<<<512, 256, 0, stream>>>(Wv, Wvb);
        cvt_kernel<<<512, 256, 0, stream>>>(Wq, Wqb);
        cvt_kernel<<<512, 256, 0, stream>>>(Wo, Wob);

        cvt_kernel<<<8192, 256, 0, stream>>>(k, Ab);
        gemm_proj<1, true><<<gblk, 256, 0, stream>>>(Ab, Wkb, bk, Et, S);

        cvt_kernel<<<8192, 256, 0, stream>>>(v, Ab);
        gemm_proj<2, true><<<gblk, 256, 0, stream>>>(Ab, Wvb, bv, Vt, nullptr);

        ctx_kernel<<<dim3(4, 16, 4), 256, 0, stream>>>(Vt, Et, ctxf);
        ctx_norm<<<1024, 256, 0, stream>>>(ctxf, S, ctxb);

        cvt_kernel<<<8192, 256, 0, stream>>>(q, Ab);
        gemm_qattn<true><<<gblk, 256, 0, stream>>>(Ab, Wqb, bq, ctxb, Vt, ec, att);

        gemm_out<true><<<gblk, 256, 0, stream>>>(att, Wob, bo, (float*)d_out);
    } else {
        // fallback: round-3 proven inline-cvt path (68.7 MB)
        unsigned short* Et   = (unsigned short*)(ws);
        unsigned short* Vt   = (unsigned short*)(ws + 33554432);
        float*          ctxf = (float*)(ws + 67108864);
        float*          S    = (float*)(ws + 68157440);
        unsigned short* ctxb = (unsigned short*)(ws + 68173824);
        unsigned short* att  = Et;

        hipMemsetAsync(S, 0, 4096 * sizeof(float), stream);
        hipMemsetAsync(ctxf, 0, 4 * 16 * 64 * 64 * sizeof(float), stream);

        gemm_proj<1, false><<<gblk, 256, 0, stream>>>(k, Wk, bk, Et, S);
        gemm_proj<2, false><<<gblk, 256, 0, stream>>>(v, Wv, bv, Vt, nullptr);
        ctx_kernel<<<dim3(4, 16, 4), 256, 0, stream>>>(Vt, Et, ctxf);
        ctx_norm<<<1024, 256, 0, stream>>>(ctxf, S, ctxb);
        gemm_qattn<false><<<gblk, 256, 0, stream>>>(q, Wq, bq, ctxb, Vt, ec, att);
        gemm_out<false><<<gblk, 256, 0, stream>>>(att, Wo, bo, (float*)d_out);
    }
}